// Round 7
// baseline (381.685 us; speedup 1.0000x reference)
//
#include <hip/hip_runtime.h>
#include <hip/hip_bf16.h>
#include <cstdint>
#include <cstddef>

typedef unsigned short u16;
typedef __bf16 bf16x8 __attribute__((ext_vector_type(8)));
typedef float f32x4 __attribute__((ext_vector_type(4)));
typedef unsigned short u16x4 __attribute__((ext_vector_type(4)));
typedef unsigned short u16x8 __attribute__((ext_vector_type(8)));

#define AS1(p) ((__attribute__((address_space(1))) void*)(p))
#define AS3(p) ((__attribute__((address_space(3))) void*)(p))

__device__ __forceinline__ float bf2f(u16 u) {
  unsigned v = ((unsigned)u) << 16; float f; __builtin_memcpy(&f, &v, 4); return f;
}
__device__ __forceinline__ u16 f2bf(float f) {
  unsigned u; __builtin_memcpy(&u, &f, 4);
  u += 0x7FFFu + ((u >> 16) & 1u);   // RNE
  return (u16)(u >> 16);
}

// ---------------- fp32 -> bf16 convert (plain) ----------------
__global__ __launch_bounds__(256) void convert_kernel(const float* __restrict__ src,
                                                      u16* __restrict__ dst, int n4) {
  int i = blockIdx.x * blockDim.x + threadIdx.x;
  int stride = gridDim.x * blockDim.x;
  for (; i < n4; i += stride) {
    float4 v = ((const float4*)src)[i];
    u16x4 o;
    o.x = f2bf(v.x); o.y = f2bf(v.y); o.z = f2bf(v.z); o.w = f2bf(v.w);
    ((u16x4*)dst)[i] = o;
  }
}

// ---------------- fp32 -> bf16 hi + lo split ----------------
__global__ __launch_bounds__(256) void convert_split_kernel(const float* __restrict__ src,
                                                            u16* __restrict__ hi,
                                                            u16* __restrict__ lo, int n4) {
  int i = blockIdx.x * blockDim.x + threadIdx.x;
  int stride = gridDim.x * blockDim.x;
  for (; i < n4; i += stride) {
    float4 v = ((const float4*)src)[i];
    u16x4 oh, ol;
    oh.x = f2bf(v.x); ol.x = f2bf(v.x - bf2f(oh.x));
    oh.y = f2bf(v.y); ol.y = f2bf(v.y - bf2f(oh.y));
    oh.z = f2bf(v.z); ol.z = f2bf(v.z - bf2f(oh.z));
    oh.w = f2bf(v.w); ol.w = f2bf(v.w - bf2f(oh.w));
    ((u16x4*)hi)[i] = oh;
    ((u16x4*)lo)[i] = ol;
  }
}

// ---------------- transpose + split: x[b,n,c] fp32 -> Xb[b,n,c] bf16, XT{hi,lo}[b,c,n] ----------------
__global__ __launch_bounds__(256) void transpose_split_kernel(const float* __restrict__ x,
                                                              u16* __restrict__ Xb,
                                                              u16* __restrict__ XThi,
                                                              u16* __restrict__ XTlo) {
  __shared__ u16 lhi[64 * 72];
  __shared__ u16 llo[64 * 72];
  const int t  = threadIdx.x;
  const int nT = blockIdx.x, cT = blockIdx.y, b = blockIdx.z;
  const size_t xbase = ((size_t)b * 4096 + nT * 64) * 1024 + cT * 64;
  const int c4 = (t & 15) * 4;
  const int r0 = t >> 4;
  const int rot_w = (t & 3) << 4;
#pragma unroll
  for (int j = 0; j < 4; ++j) {
    int r = r0 + j * 16;
    float4 v = *(const float4*)(x + xbase + (size_t)r * 1024 + c4);
    u16x4 hi;
    hi.x = f2bf(v.x); hi.y = f2bf(v.y); hi.z = f2bf(v.z); hi.w = f2bf(v.w);
    *(u16x4*)(Xb + xbase + (size_t)r * 1024 + c4) = hi;
    u16 lo[4];
    lo[0] = f2bf(v.x - bf2f(hi.x)); lo[1] = f2bf(v.y - bf2f(hi.y));
    lo[2] = f2bf(v.z - bf2f(hi.z)); lo[3] = f2bf(v.w - bf2f(hi.w));
    u16 hia[4] = { hi.x, hi.y, hi.z, hi.w };
    const int rs = r ^ rot_w;
#pragma unroll
    for (int i = 0; i < 4; ++i) {
      lhi[(c4 + i) * 72 + rs] = hia[i];
      llo[(c4 + i) * 72 + rs] = lo[i];
    }
  }
  __syncthreads();
  const int c  = t >> 2;
  const int n0 = (t & 3) * 16;
  const int rot_r = ((t >> 4) & 3) << 4;
  const int nA = n0 ^ rot_r;
  const size_t tbase = ((size_t)b * 1024 + cT * 64 + c) * 4096 + nT * 64 + n0;
  *(u16x8*)(XThi + tbase)     = *(const u16x8*)(lhi + c * 72 + nA);
  *(u16x8*)(XThi + tbase + 8) = *(const u16x8*)(lhi + c * 72 + nA + 8);
  *(u16x8*)(XTlo + tbase)     = *(const u16x8*)(llo + c * 72 + nA);
  *(u16x8*)(XTlo + tbase + 8) = *(const u16x8*)(llo + c * 72 + nA + 8);
}

// ---------------- deep-pipelined 256x256 GEMM: C[M,N] = A[M,K] * B[N,K]^T ----------------
template<bool OUT_BF16, bool HAS_BIAS>
__global__ __launch_bounds__(512, 2) void gemm_pipe(const u16* __restrict__ A,
                                                    const u16* __restrict__ B,
                                                    void* __restrict__ Cv,
                                                    const float* __restrict__ bias,
                                                    int M, int N, int K,
                                                    size_t sA, size_t sB, size_t sC) {
  __shared__ __align__(16) u16 lds[4][2][8192];   // [ring][A|B][256 rows x 32 k] = 128 KiB
  const int tid  = threadIdx.x;
  const int lane = tid & 63;
  const int wave = tid >> 6;
  const int wm = wave >> 2, wn = wave & 3;
  const int rowTile = blockIdx.x * 256;
  const int colTile = blockIdx.y * 256;
  A += (size_t)blockIdx.z * sA;
  B += (size_t)blockIdx.z * sB;

  size_t srcA[2], srcB[2];
  int ldsOff[2];
#pragma unroll
  for (int j = 0; j < 2; ++j) {
    const int L = j * 512 + tid;           // 16B slot index 0..1023
    const int sr = L >> 3;                 // 128B superrow (2 rows)
    const int slot = (L & 7) ^ (sr & 7);   // logical slot within superrow
    const int r  = (sr << 1) | (slot >> 2);
    const int kq = slot & 3;
    srcA[j] = (size_t)(rowTile + r) * K + kq * 8;
    srcB[j] = (size_t)(colTile + r) * K + kq * 8;
    ldsOff[j] = (j * 512 + (tid & 448)) * 16;
  }

  const int m15 = lane & 15, kq4 = lane >> 4;
  const int r0a = wm * 128 + m15, sa0 = r0a >> 1;
  const int idxA0 = sa0 * 64 + (((((r0a & 1) << 2) | kq4)) ^ (sa0 & 7)) * 8;
  const int r0b = wn * 64 + m15, sb0 = r0b >> 1;
  const int idxB0 = sb0 * 64 + (((((r0b & 1) << 2) | kq4)) ^ (sb0 & 7)) * 8;

  const int NT = K >> 5;

  auto stageA = [&](int tt) {
    char* d = (char*)&lds[tt & 3][0][0];
    const int kt = tt << 5;
#pragma unroll
    for (int j = 0; j < 2; ++j)
      __builtin_amdgcn_global_load_lds(AS1(A + srcA[j] + kt), AS3(d + ldsOff[j]), 16, 0, 0);
  };
  auto stageB = [&](int tt) {
    char* d = (char*)&lds[tt & 3][1][0];
    const int kt = tt << 5;
#pragma unroll
    for (int j = 0; j < 2; ++j)
      __builtin_amdgcn_global_load_lds(AS1(B + srcB[j] + kt), AS3(d + ldsOff[j]), 16, 0, 0);
  };

  stageA(0); stageB(0);
  if (NT > 1) { stageA(1); stageB(1); }
  if (NT > 2) { stageA(2); stageB(2); }
  if (NT > 2) asm volatile("s_waitcnt vmcnt(8)" ::: "memory");
  else        asm volatile("s_waitcnt vmcnt(0)" ::: "memory");
  __builtin_amdgcn_sched_barrier(0);
  __builtin_amdgcn_s_barrier();
  __builtin_amdgcn_sched_barrier(0);

  f32x4 acc[8][4] = {};
  for (int t = 0; t < NT; ++t) {
    const u16* bufA = &lds[t & 3][0][0];
    const u16* bufB = &lds[t & 3][1][0];
    bf16x8 a[8], bfr[4];
#pragma unroll
    for (int ni = 0; ni < 4; ++ni) bfr[ni] = *(const bf16x8*)(bufB + idxB0 + ni * 512);
#pragma unroll
    for (int mi = 0; mi < 4; ++mi) a[mi] = *(const bf16x8*)(bufA + idxA0 + mi * 512);
    if (t + 3 < NT) stageA(t + 3);
    __builtin_amdgcn_sched_barrier(0);
    __builtin_amdgcn_s_barrier();
    __builtin_amdgcn_sched_barrier(0);
    __builtin_amdgcn_s_setprio(1);
#pragma unroll
    for (int mi = 0; mi < 4; ++mi)
#pragma unroll
      for (int ni = 0; ni < 4; ++ni)
        acc[mi][ni] = __builtin_amdgcn_mfma_f32_16x16x32_bf16(a[mi], bfr[ni], acc[mi][ni], 0, 0, 0);
    __builtin_amdgcn_s_setprio(0);
    __builtin_amdgcn_sched_barrier(0);
    __builtin_amdgcn_s_barrier();
    __builtin_amdgcn_sched_barrier(0);
#pragma unroll
    for (int mi = 4; mi < 8; ++mi) a[mi] = *(const bf16x8*)(bufA + idxA0 + mi * 512);
    if (t + 3 < NT) stageB(t + 3);
    __builtin_amdgcn_sched_barrier(0);
    __builtin_amdgcn_s_barrier();
    __builtin_amdgcn_sched_barrier(0);
    __builtin_amdgcn_s_setprio(1);
#pragma unroll
    for (int mi = 4; mi < 8; ++mi)
#pragma unroll
      for (int ni = 0; ni < 4; ++ni)
        acc[mi][ni] = __builtin_amdgcn_mfma_f32_16x16x32_bf16(a[mi], bfr[ni], acc[mi][ni], 0, 0, 0);
    __builtin_amdgcn_s_setprio(0);
    if (t < NT - 1) {
      if (t + 3 < NT)      asm volatile("s_waitcnt vmcnt(8)" ::: "memory");
      else if (t + 2 < NT) asm volatile("s_waitcnt vmcnt(4)" ::: "memory");
      else                 asm volatile("s_waitcnt vmcnt(0)" ::: "memory");
    }
    __builtin_amdgcn_sched_barrier(0);
    __builtin_amdgcn_s_barrier();
    __builtin_amdgcn_sched_barrier(0);
  }

  const int crow0 = rowTile + wm * 128 + (lane >> 4) * 4;
  const int ccol0 = colTile + wn * 64 + m15;
  if constexpr (OUT_BF16) {
    u16* C = (u16*)Cv + (size_t)blockIdx.z * sC;
#pragma unroll
    for (int mi = 0; mi < 8; ++mi)
#pragma unroll
      for (int ni = 0; ni < 4; ++ni) {
        const int col = ccol0 + ni * 16;
        const float bv = HAS_BIAS ? bias[col] : 0.f;
#pragma unroll
        for (int r = 0; r < 4; ++r)
          C[(size_t)(crow0 + mi * 16 + r) * N + col] = f2bf(acc[mi][ni][r] + bv);
      }
  } else {
    float* C = (float*)Cv + (size_t)blockIdx.z * sC;
#pragma unroll
    for (int mi = 0; mi < 8; ++mi)
#pragma unroll
      for (int ni = 0; ni < 4; ++ni) {
        const int col = ccol0 + ni * 16;
        const float bv = HAS_BIAS ? bias[col] : 0.f;
#pragma unroll
        for (int r = 0; r < 4; ++r)
          C[(size_t)(crow0 + mi * 16 + r) * N + col] = acc[mi][ni][r] + bv;
      }
  }
}

// ---------------- 4-tensor (hi/lo x A/B) pipelined 128x128 K-loop core (wave tile 64x32) ----------------
template<int L>
__device__ __forceinline__ void pipe4_core(const u16* __restrict__ pAh,
                                           const u16* __restrict__ pAl,
                                           const u16* __restrict__ pBh,
                                           const u16* __restrict__ pBl,
                                           u16* lds, int ldsByteOff,
                                           int idxA0, int idxB0, int bOff, int NT,
                                           f32x4 acc[4][2]) {
  auto stage2A = [&](int tt) {
    u16* d = lds + (tt & 3) * 16384;
    const int kt = tt << 5;
    __builtin_amdgcn_global_load_lds(AS1(pAh + kt), AS3((char*)d + ldsByteOff), 16, 0, 0);
    __builtin_amdgcn_global_load_lds(AS1(pAl + kt), AS3((char*)(d + 4096) + ldsByteOff), 16, 0, 0);
  };
  auto stage2B = [&](int tt) {
    if constexpr (L == 4) {
      u16* d = lds + (tt & 3) * 16384 + 8192;
      const int kt = tt << 5;
      __builtin_amdgcn_global_load_lds(AS1(pBh + kt), AS3((char*)d + ldsByteOff), 16, 0, 0);
      __builtin_amdgcn_global_load_lds(AS1(pBl + kt), AS3((char*)(d + 4096) + ldsByteOff), 16, 0, 0);
    }
  };

  stage2A(0); stage2B(0);
  stage2A(1); stage2B(1);
  stage2A(2); stage2B(2);
  if constexpr (L == 4) asm volatile("s_waitcnt vmcnt(8)" ::: "memory");
  else                  asm volatile("s_waitcnt vmcnt(4)" ::: "memory");
  __builtin_amdgcn_sched_barrier(0);
  __builtin_amdgcn_s_barrier();
  __builtin_amdgcn_sched_barrier(0);

  for (int t = 0; t < NT; ++t) {
    const u16* base = lds + (t & 3) * 16384;
    bf16x8 ah[4], al[4], bh[2], bl[2];
    bh[0] = *(const bf16x8*)(base + bOff + idxB0);
    bh[1] = *(const bf16x8*)(base + bOff + idxB0 + 512);
    bl[0] = *(const bf16x8*)(base + bOff + 4096 + idxB0);
    bl[1] = *(const bf16x8*)(base + bOff + 4096 + idxB0 + 512);
    ah[0] = *(const bf16x8*)(base + idxA0);
    ah[1] = *(const bf16x8*)(base + idxA0 + 512);
    al[0] = *(const bf16x8*)(base + 4096 + idxA0);
    al[1] = *(const bf16x8*)(base + 4096 + idxA0 + 512);
    if (t + 3 < NT) stage2A(t + 3);
    __builtin_amdgcn_sched_barrier(0);
    __builtin_amdgcn_s_barrier();
    __builtin_amdgcn_sched_barrier(0);
    __builtin_amdgcn_s_setprio(1);
#pragma unroll
    for (int mi = 0; mi < 2; ++mi)
#pragma unroll
      for (int ni = 0; ni < 2; ++ni) {
        acc[mi][ni] = __builtin_amdgcn_mfma_f32_16x16x32_bf16(ah[mi], bh[ni], acc[mi][ni], 0, 0, 0);
        acc[mi][ni] = __builtin_amdgcn_mfma_f32_16x16x32_bf16(ah[mi], bl[ni], acc[mi][ni], 0, 0, 0);
        acc[mi][ni] = __builtin_amdgcn_mfma_f32_16x16x32_bf16(al[mi], bh[ni], acc[mi][ni], 0, 0, 0);
      }
    __builtin_amdgcn_s_setprio(0);
    __builtin_amdgcn_sched_barrier(0);
    __builtin_amdgcn_s_barrier();
    __builtin_amdgcn_sched_barrier(0);
    ah[2] = *(const bf16x8*)(base + idxA0 + 1024);
    ah[3] = *(const bf16x8*)(base + idxA0 + 1536);
    al[2] = *(const bf16x8*)(base + 4096 + idxA0 + 1024);
    al[3] = *(const bf16x8*)(base + 4096 + idxA0 + 1536);
    if (t + 3 < NT) stage2B(t + 3);
    __builtin_amdgcn_sched_barrier(0);
    __builtin_amdgcn_s_barrier();
    __builtin_amdgcn_sched_barrier(0);
    __builtin_amdgcn_s_setprio(1);
#pragma unroll
    for (int mi = 2; mi < 4; ++mi)
#pragma unroll
      for (int ni = 0; ni < 2; ++ni) {
        acc[mi][ni] = __builtin_amdgcn_mfma_f32_16x16x32_bf16(ah[mi], bh[ni], acc[mi][ni], 0, 0, 0);
        acc[mi][ni] = __builtin_amdgcn_mfma_f32_16x16x32_bf16(ah[mi], bl[ni], acc[mi][ni], 0, 0, 0);
        acc[mi][ni] = __builtin_amdgcn_mfma_f32_16x16x32_bf16(al[mi], bh[ni], acc[mi][ni], 0, 0, 0);
      }
    __builtin_amdgcn_s_setprio(0);
    if (t < NT - 1) {
      if constexpr (L == 4) {
        if (t + 3 < NT)      asm volatile("s_waitcnt vmcnt(8)" ::: "memory");
        else if (t + 2 < NT) asm volatile("s_waitcnt vmcnt(4)" ::: "memory");
        else                 asm volatile("s_waitcnt vmcnt(0)" ::: "memory");
      } else {
        if (t + 3 < NT)      asm volatile("s_waitcnt vmcnt(4)" ::: "memory");
        else if (t + 2 < NT) asm volatile("s_waitcnt vmcnt(2)" ::: "memory");
        else                 asm volatile("s_waitcnt vmcnt(0)" ::: "memory");
      }
    }
    __builtin_amdgcn_sched_barrier(0);
    __builtin_amdgcn_s_barrier();
    __builtin_amdgcn_sched_barrier(0);
  }
}

// ---------------- 4-tensor K-pair pipelined 128x128 core, wave tile 64x64 (K-parity halves) ----------------
template<int L>
__device__ __forceinline__ void pipe4k_core(const u16* __restrict__ pAh,
                                            const u16* __restrict__ pAl,
                                            const u16* __restrict__ pBh,
                                            const u16* __restrict__ pBl,
                                            u16* lds, int ldsByteOff,
                                            int idxA0, int idxB0, int bOff,
                                            int NT, int half,
                                            f32x4 acc[4][4]) {
  auto stage = [&](int tt) {
    u16* d = lds + (tt & 3) * 16384;
    const int kt = tt << 5;
    __builtin_amdgcn_global_load_lds(AS1(pAh + kt), AS3((char*)d + ldsByteOff), 16, 0, 0);
    __builtin_amdgcn_global_load_lds(AS1(pAl + kt), AS3((char*)(d + 4096) + ldsByteOff), 16, 0, 0);
    if constexpr (L == 4) {
      __builtin_amdgcn_global_load_lds(AS1(pBh + kt), AS3((char*)(d + 8192) + ldsByteOff), 16, 0, 0);
      __builtin_amdgcn_global_load_lds(AS1(pBl + kt), AS3((char*)(d + 12288) + ldsByteOff), 16, 0, 0);
    }
  };

  stage(0); stage(1); stage(2); stage(3);
  if constexpr (L == 4) asm volatile("s_waitcnt vmcnt(8)" ::: "memory");
  else                  asm volatile("s_waitcnt vmcnt(4)" ::: "memory");
  __builtin_amdgcn_sched_barrier(0);
  __builtin_amdgcn_s_barrier();
  __builtin_amdgcn_sched_barrier(0);

  const int npairs = NT >> 1;
  for (int i = 0; i < npairs; ++i) {
    const u16* base = lds + ((2 * i + half) & 3) * 16384;
    bf16x8 ah[4], al[4], bh[4], bl[4];
#pragma unroll
    for (int ni = 0; ni < 4; ++ni) {
      bh[ni] = *(const bf16x8*)(base + bOff + idxB0 + ni * 512);
      bl[ni] = *(const bf16x8*)(base + bOff + 4096 + idxB0 + ni * 512);
    }
    ah[0] = *(const bf16x8*)(base + idxA0);
    ah[1] = *(const bf16x8*)(base + idxA0 + 512);
    al[0] = *(const bf16x8*)(base + 4096 + idxA0);
    al[1] = *(const bf16x8*)(base + 4096 + idxA0 + 512);
    __builtin_amdgcn_sched_barrier(0);
    __builtin_amdgcn_s_barrier();
    __builtin_amdgcn_sched_barrier(0);
    __builtin_amdgcn_s_setprio(1);
#pragma unroll
    for (int mi = 0; mi < 2; ++mi)
#pragma unroll
      for (int ni = 0; ni < 4; ++ni) {
        acc[mi][ni] = __builtin_amdgcn_mfma_f32_16x16x32_bf16(ah[mi], bh[ni], acc[mi][ni], 0, 0, 0);
        acc[mi][ni] = __builtin_amdgcn_mfma_f32_16x16x32_bf16(ah[mi], bl[ni], acc[mi][ni], 0, 0, 0);
        acc[mi][ni] = __builtin_amdgcn_mfma_f32_16x16x32_bf16(al[mi], bh[ni], acc[mi][ni], 0, 0, 0);
      }
    __builtin_amdgcn_s_setprio(0);
    __builtin_amdgcn_sched_barrier(0);
    __builtin_amdgcn_s_barrier();
    __builtin_amdgcn_sched_barrier(0);
    ah[2] = *(const bf16x8*)(base + idxA0 + 1024);
    ah[3] = *(const bf16x8*)(base + idxA0 + 1536);
    al[2] = *(const bf16x8*)(base + 4096 + idxA0 + 1024);
    al[3] = *(const bf16x8*)(base + 4096 + idxA0 + 1536);
    __builtin_amdgcn_sched_barrier(0);
    __builtin_amdgcn_s_barrier();
    __builtin_amdgcn_sched_barrier(0);
    if (i + 2 < npairs) { stage(2 * i + 4); stage(2 * i + 5); }
    __builtin_amdgcn_sched_barrier(0);
    __builtin_amdgcn_s_setprio(1);
#pragma unroll
    for (int mi = 2; mi < 4; ++mi)
#pragma unroll
      for (int ni = 0; ni < 4; ++ni) {
        acc[mi][ni] = __builtin_amdgcn_mfma_f32_16x16x32_bf16(ah[mi], bh[ni], acc[mi][ni], 0, 0, 0);
        acc[mi][ni] = __builtin_amdgcn_mfma_f32_16x16x32_bf16(ah[mi], bl[ni], acc[mi][ni], 0, 0, 0);
        acc[mi][ni] = __builtin_amdgcn_mfma_f32_16x16x32_bf16(al[mi], bh[ni], acc[mi][ni], 0, 0, 0);
      }
    __builtin_amdgcn_s_setprio(0);
    if (i < npairs - 1) {
      if (i + 2 < npairs) {
        if constexpr (L == 4) asm volatile("s_waitcnt vmcnt(8)" ::: "memory");
        else                  asm volatile("s_waitcnt vmcnt(4)" ::: "memory");
      } else {
        asm volatile("s_waitcnt vmcnt(0)" ::: "memory");
      }
    }
    __builtin_amdgcn_sched_barrier(0);
    __builtin_amdgcn_s_barrier();
    __builtin_amdgcn_sched_barrier(0);
  }
}

// ---------------- pipelined symmetric Gram: uniform 72u ribbon jobs + atomic single-slice ----------------
// Per batch: 36 upper-tri 128-tiles x 128 K-tiles = 4608 units, cut into 64 jobs of exactly 72
// (grid 256 = 1 block/CU, perfectly balanced; pieces per job <= 2, min piece 8, always even).
// All tiles computed in upper orientation only; flush via atomicAdd into pre-zeroed single-slice
// Gpart[b]. Reduce forms G(r,c) = s(r,c) + s(c,r)^T (mirror slots are zero).
__global__ __launch_bounds__(512, 2) void gram_pipe(const u16* __restrict__ XThi,
                                                    const u16* __restrict__ XTlo,
                                                    float* __restrict__ Gpart) {
  __shared__ __align__(16) u16 ldsmem[4 * 4 * 4096];   // 128 KiB ring; reused for flush exchange
  const int tid = threadIdx.x, lane = tid & 63, wave = tid >> 6;
  const int q = wave & 3, half = wave >> 2;
  const int qm = q >> 1, qn = q & 1;
  const int b = blockIdx.x & 3, j = blockIdx.x >> 2;   // 64 ribbon jobs x 4 batches
  const u16* Ah = XThi + ((size_t)b << 22);
  const u16* Al = XTlo + ((size_t)b << 22);
  float* out = Gpart + ((size_t)b << 20);

  const int sr = tid >> 3;
  const int slot = (tid & 7) ^ (sr & 7);
  const int r = (sr << 1) | (slot >> 2);
  const int kq8 = (slot & 3) * 8;
  const int ldsByteOff = (tid & 448) * 16;

  const int m15 = lane & 15, kq4 = lane >> 4;
  const int r0a = qm * 64 + m15, sa0 = r0a >> 1;
  const int idxA0 = sa0 * 64 + (((((r0a & 1) << 2) | kq4)) ^ (sa0 & 7)) * 8;
  const int r0b = qn * 64 + m15, sb0 = r0b >> 1;
  const int idxB0 = sb0 * 64 + (((((r0b & 1) << 2) | kq4)) ^ (sb0 & 7)) * 8;
  const int rr = (lane >> 4) * 4;

  int u0 = j * 72;
  const int u1 = u0 + 72;
  while (u0 < u1) {
    const int tile = u0 >> 7;
    const int ks = u0 & 127;
    int len = 128 - ks;
    if (u0 + len > u1) len = u1 - u0;
    // tile -> (rt, ct), upper-tri incl diag (rt<=ct)
    int t2 = tile, rt = 0;
    while (t2 >= 8 - rt) { t2 -= 8 - rt; ++rt; }
    const int ct = rt + t2;
    const int rowTile = rt * 128, colTile = ct * 128;
    const int k0 = ks * 32;
    const u16* pAh = Ah + (size_t)(rowTile + r) * 4096 + k0 + kq8;
    const u16* pAl = Al + (size_t)(rowTile + r) * 4096 + k0 + kq8;
    const u16* pBh = Ah + (size_t)(colTile + r) * 4096 + k0 + kq8;
    const u16* pBl = Al + (size_t)(colTile + r) * 4096 + k0 + kq8;

    f32x4 acc[4][4] = {};
    pipe4k_core<4>(pAh, pAl, pBh, pBl, ldsmem, ldsByteOff, idxA0, idxB0, 8192, len, half, acc);

    // flush: half-1 stores to LDS (68-padded col-major), half-0 adds + atomicAdd to Gpart
    float* red = (float*)ldsmem;
    if (half) {
#pragma unroll
      for (int mi = 0; mi < 4; ++mi)
#pragma unroll
        for (int ni = 0; ni < 4; ++ni)
          *(f32x4*)(red + q * 4352 + (ni * 16 + m15) * 68 + mi * 16 + rr) = acc[mi][ni];
    }
    __syncthreads();
    if (!half) {
      const int crow0 = rowTile + qm * 64 + rr;
      const int ccol0 = colTile + qn * 64 + m15;
#pragma unroll
      for (int mi = 0; mi < 4; ++mi)
#pragma unroll
        for (int ni = 0; ni < 4; ++ni) {
          f32x4 v = *(const f32x4*)(red + q * 4352 + (ni * 16 + m15) * 68 + mi * 16 + rr);
          v += acc[mi][ni];
#pragma unroll
          for (int r4 = 0; r4 < 4; ++r4)
            atomicAdd(&out[(size_t)(crow0 + mi * 16 + r4) * 1024 + ccol0 + ni * 16], v[r4]);
        }
    }
    __syncthreads();   // red reads done before next piece's staging overwrites ldsmem
    u0 += len;
  }
}

// ---------------- tiled reduce (single slice): G = s(r,c) [+ s(c,r)^T if off-diag-128] ----------------
__global__ __launch_bounds__(256) void gram_reduce_split(const float* __restrict__ Gp,
                                                         u16* __restrict__ Ghi,
                                                         u16* __restrict__ Glo) {
  const int rt = blockIdx.x, ct = blockIdx.y, b = blockIdx.z;  // 64x64 tiles
  const bool diag128 = (rt >> 1) == (ct >> 1);
  const float* s0 = Gp + ((size_t)b << 20);
  __shared__ float lT[64 * 68];
  const int t = threadIdx.x;
  const int r = t >> 2;
  const int c16 = (t & 3) * 16;

  if (!diag128) {
    const size_t bb = (size_t)(ct * 64 + r) * 1024 + rt * 64 + c16;
#pragma unroll
    for (int q = 0; q < 4; ++q)
      *(float4*)(lT + r * 68 + c16 + q * 4) = *(const float4*)(s0 + bb + q * 4);
    __syncthreads();
  }

  const size_t ab = (size_t)(rt * 64 + r) * 1024 + ct * 64 + c16;
  const size_t ob = ((size_t)b << 20) + ab;
#pragma unroll
  for (int q = 0; q < 4; ++q) {
    float4 v0 = *(const float4*)(s0 + ab + q * 4);
    float g[4] = { v0.x, v0.y, v0.z, v0.w };
    if (!diag128) {
#pragma unroll
      for (int i = 0; i < 4; ++i) g[i] += lT[(c16 + q * 4 + i) * 68 + r];
    }
    u16x4 oh, ol;
    oh.x = f2bf(g[0]); ol.x = f2bf(g[0] - bf2f(oh.x));
    oh.y = f2bf(g[1]); ol.y = f2bf(g[1] - bf2f(oh.y));
    oh.z = f2bf(g[2]); ol.z = f2bf(g[2] - bf2f(oh.z));
    oh.w = f2bf(g[3]); ol.w = f2bf(g[3] - bf2f(oh.w));
    *(u16x4*)(Ghi + ob + q * 4) = oh;
    *(u16x4*)(Glo + ob + q * 4) = ol;
  }
}

// ---------------- pipelined T' = Wq * G (G symmetric), pipe4_core, split-bf16 out ----------------
// 256 uniform blocks (64 tiles x 4 batches), K=1024: one block per CU, one round.
__global__ __launch_bounds__(512, 2) void tprime_pipe(const u16* __restrict__ Wqh,
                                                      const u16* __restrict__ Wql,
                                                      const u16* __restrict__ Ghi,
                                                      const u16* __restrict__ Glo,
                                                      u16* __restrict__ Tph,
                                                      u16* __restrict__ Tpl) {
  __shared__ __align__(16) u16 lds[4 * 4 * 4096];   // 128 KiB
  const int tid = threadIdx.x, lane = tid & 63, wave = tid >> 6;
  const int wm = wave >> 2, wn = wave & 3;
  const int bid = blockIdx.x;
  const int b = bid & 3, tile = bid >> 2;
  const int rowTile = (tile >> 3) * 128, colTile = (tile & 7) * 128;
  const size_t zoff = (size_t)b << 20;

  const int sr = tid >> 3;
  const int slot = (tid & 7) ^ (sr & 7);
  const int r = (sr << 1) | (slot >> 2);
  const int kq8 = (slot & 3) * 8;
  const u16* pAh = Wqh + (size_t)(rowTile + r) * 1024 + kq8;
  const u16* pAl = Wql + (size_t)(rowTile + r) * 1024 + kq8;
  const u16* pBh = Ghi + zoff + (size_t)(colTile + r) * 1024 + kq8;
  const u16* pBl = Glo + zoff + (size_t)(colTile + r) * 1024 + kq8;
  const int ldsByteOff = (tid & 448) * 16;

  const int m15 = lane & 15, kq4 = lane >> 4;
  const int r0a = wm * 64 + m15, sa0 = r0a >> 1;
  const int idxA0 = sa0 * 64 + (((((r0a & 1) << 2) | kq4)) ^ (sa0 & 7)) * 8;
  const int r0b = wn * 32 + m15, sb0 = r0b >> 1;
  const int idxB0 = sb0 * 64 + (((((r0b & 1) << 2) | kq4)) ^ (sb0 & 7)) * 8;

  f32x4 acc[4][2] = {};
  pipe4_core<4>(pAh, pAl, pBh, pBl, lds, ldsByteOff, idxA0, idxB0, 8192, 32, acc);

  const int crow0 = rowTile + wm * 64 + (lane >> 4) * 4;
  const int ccol0 = colTile + wn * 32 + m15;
#pragma unroll
  for (int mi = 0; mi < 4; ++mi)
#pragma unroll
    for (int ni = 0; ni < 2; ++ni)
#pragma unroll
      for (int r4 = 0; r4 < 4; ++r4) {
        float v = acc[mi][ni][r4];
        u16 hi = f2bf(v);
        u16 lo = f2bf(v - bf2f(hi));
        size_t off = zoff + (size_t)(crow0 + mi * 16 + r4) * 1024 + ccol0 + ni * 16;
        Tph[off] = hi;
        Tpl[off] = lo;
      }
}

// ---------------- fused S + softmax -> attn^T, 512 thr K-parity + swizzled LDS ----------------
__global__ __launch_bounds__(512) void s_softmax_kernel(const u16* __restrict__ Wqh,
                                                        const u16* __restrict__ Wql,
                                                        const u16* __restrict__ Tph,
                                                        const u16* __restrict__ Tpl,
                                                        const float* __restrict__ alpha,
                                                        u16* __restrict__ attnT) {
  const int h = blockIdx.x, b = blockIdx.y;
  const int tid = threadIdx.x, lane = tid & 63, wave = tid >> 6;
  const int half = wave >> 2, w4 = wave & 3;
  __shared__ __align__(16) u16 sm[2][4][64 * 32];   // [set][Ah,Al,Bh,Bl] = 32 KiB

  const size_t aBase = (size_t)(1024 + h * 64) * 1024;
  const size_t bBase = ((size_t)b << 20) + (size_t)(h * 64) * 1024;

  const int tid2 = tid & 255;
  const int sr = tid2 >> 3;
  const int slot = (tid2 & 7) ^ (sr & 7);
  const int r = (sr << 1) | (slot >> 2);
  const int kq8 = (slot & 3) * 8;
  const u16* pAh = Wqh + aBase + (size_t)r * 1024 + kq8;
  const u16* pAl = Wql + aBase + (size_t)r * 1024 + kq8;
  const u16* pBh = Tph + bBase + (size_t)r * 1024 + kq8;
  const u16* pBl = Tpl + bBase + (size_t)r * 1024 + kq8;
  const int off = (tid2 & 192) * 16;

  const int m = lane & 15, kq4 = lane >> 4;
  const int rA = w4 * 16 + m, sA0 = rA >> 1;
  const int idxA = sA0 * 64 + (((((rA & 1) << 2) | kq4)) ^ (sA0 & 7)) * 8;
  int idxB[4];
#pragma unroll
  for (int cb = 0; cb < 4; ++cb) {
    const int rB = cb * 16 + m, sB0 = rB >> 1;
    idxB[cb] = sB0 * 64 + (((((rB & 1) << 2) | kq4)) ^ (sB0 & 7)) * 8;
  }

  f32x4 acc[4] = {};
  for (int i = 0; i < 16; ++i) {
    const int kt = (2 * i + half) * 32;
    __builtin_amdgcn_global_load_lds(AS1(pAh + kt), AS3((char*)&sm[half][0][0] + off), 16, 0, 0);
    __builtin_amdgcn_global_load_lds(AS1(pAl + kt), AS3((char*)&sm[half][1][0] + off), 16, 0, 0);
    __builtin_amdgcn_global_load_lds(AS1(pBh + kt), AS3((char*)&sm[half][2][0] + off), 16, 0, 0);
    __builtin_amdgcn_global_load_lds(AS1(pBl + kt), AS3((char*)&sm[half][3][0] + off), 16, 0, 0);
    __syncthreads();
    bf16x8 ah = *(const bf16x8*)(&sm[half][0][0] + idxA);
    bf16x8 al = *(const bf16x8*)(&sm[half][1][0] + idxA);
#pragma unroll
    for (int cb = 0; cb < 4; ++cb) {
      bf16x8 bh = *(const bf16x8*)(&sm[half][2][0] + idxB[cb]);
      bf16x8 bl = *(const bf16x8*)(&sm[half][3][0] + idxB[cb]);
      acc[cb] = __builtin_amdgcn_mfma_f32_16x16x32_bf16(ah, bh, acc[cb], 0, 0, 0);
      acc[cb] = __builtin_amdgcn_mfma_f32_16x16x32_bf16(ah, bl, acc[cb], 0, 0, 0);
      acc[cb] = __builtin_amdgcn_mfma_f32_16x16x32_bf16(al, bh, acc[cb], 0, 0, 0);
    }
    __syncthreads();
  }

  float* red = (float*)&sm[0][0][0];
  const int rbase = (w4 * 64 + lane) * 20;
  if (half) {
#pragma unroll
    for (int cb = 0; cb < 4; ++cb)
      *(f32x4*)(red + rbase + cb * 4) = acc[cb];
  }
  __syncthreads();
  if (!half) {
#pragma unroll
    for (int cb = 0; cb < 4; ++cb)
      acc[cb] += *(const f32x4*)(red + rbase + cb * 4);

    const float invA = 1.f / alpha[h];
    const int g = lane >> 4;
    const size_t obase = (size_t)(b * 16 + h) * 4096;
#pragma unroll
    for (int rr = 0; rr < 4; ++rr) {
      int d = w4 * 16 + g * 4 + rr;
      float s[4];
#pragma unroll
      for (int cb = 0; cb < 4; ++cb) s[cb] = acc[cb][rr] * invA;
      float mx = fmaxf(fmaxf(s[0], s[1]), fmaxf(s[2], s[3]));
#pragma unroll
      for (int o = 1; o < 16; o <<= 1) mx = fmaxf(mx, __shfl_xor(mx, o, 64));
      float e[4]; float sum = 0.f;
#pragma unroll
      for (int cb = 0; cb < 4; ++cb) { e[cb] = __expf(s[cb] - mx); sum += e[cb]; }
#pragma unroll
      for (int o = 1; o < 16; o <<= 1) sum += __shfl_xor(sum, o, 64);
      float inv = 1.f / sum;
#pragma unroll
      for (int cb = 0; cb < 4; ++cb) {
        int e_idx = cb * 16 + (lane & 15);
        attnT[obase + (size_t)e_idx * 64 + d] = f2bf(e[cb] * inv);
      }
    }
  }
}

// ---------------- M_b[o, h*64+e] = sum_d Wproj[o, h*64+d] * attn_bh[d,e] ----------------
__global__ __launch_bounds__(256) void m_build_kernel(const u16* __restrict__ Wpb,
                                                      const u16* __restrict__ attnT,
                                                      u16* __restrict__ Mb) {
  const int oT = blockIdx.x, h = blockIdx.y, b = blockIdx.z;
  const int tid = threadIdx.x, lane = tid & 63, wave = tid >> 6;
  __shared__ __align__(16) u16 lA[128 * 64];   // Wproj tile [o 128][d 64]
  __shared__ __align__(16) u16 lB[64 * 64];    // attnT [e 64][d 64]
  const int bh = b * 16 + h;
#pragma unroll
  for (int i = 0; i < 4; ++i) {
    int idx = i * 256 + tid;
    int row = idx >> 3;
    int kc  = (idx & 7) * 8;
    int ldsOff = (i * 256 + (tid & 192)) * 16;
    __builtin_amdgcn_global_load_lds(AS1(Wpb + (size_t)(oT * 128 + row) * 1024 + h * 64 + kc),
                                     AS3((char*)lA + ldsOff), 16, 0, 0);
  }
#pragma unroll
  for (int i = 0; i < 2; ++i) {
    int idx = i * 256 + tid;
    int ldsOff = (i * 256 + (tid & 192)) * 16;
    __builtin_amdgcn_global_load_lds(AS1(attnT + (size_t)bh * 4096 + idx * 8),
                                     AS3((char*)lB + ldsOff), 16, 0, 0);
  }
  __syncthreads();
  const int m  = lane & 15;
  const int ko = (lane >> 4) * 8;
  const int wr = wave * 32;
  f32x4 acc[2][4] = {};
#pragma unroll
  for (int ks = 0; ks < 2; ++ks) {
#pragma unroll
    for (int rb = 0; rb < 2; ++rb) {
      bf16x8 a = *(const bf16x8*)(lA + (wr + rb * 16 + m) * 64 + ks * 32 + ko);
#pragma unroll
      for (int cb = 0; cb < 4; ++cb) {
        bf16x8 bb = *(const bf16x8*)(lB + (cb * 16 + m) * 64 + ks * 32 + ko);
        acc[rb][cb] = __builtin_amdgcn_mfma_f32_16x16x32_bf16(a, bb, acc[rb][cb], 0, 0, 0);
      }
    }
  }
  u16* out = Mb + ((size_t)b << 20);
#pragma unroll
  for (int rb = 0; rb < 2; ++rb)
#pragma unroll
    for (int cb = 0; cb < 4; ++cb) {
      int col = h * 64 + cb * 16 + (lane & 15);
#pragma unroll
      for (int r = 0; r < 4; ++r) {
        int row = oT * 128 + wr + rb * 16 + (lane >> 4) * 4 + r;
        out[(size_t)row * 1024 + col] = f2bf(acc[rb][cb][r]);
      }
    }
}

extern "C" void kernel_launch(void* const* d_in, const int* in_sizes, int n_in,
                              void* d_out, int out_size, void* d_ws, size_t ws_size,
                              hipStream_t stream) {
  const float* x     = (const float*)d_in[0];
  const float* Wqkv  = (const float*)d_in[3];
  const float* Wproj = (const float*)d_in[4];
  const float* bproj = (const float*)d_in[5];
  const float* alpha = (const float*)d_in[6];

  char* ws = (char*)d_ws;
  // Region A (32 MiB): Xb -> Gpart(16 MB, single slice) -> Mb
  u16*   Xb     = (u16*)ws;
  float* Gpart  = (float*)ws;
  u16*   Mb     = (u16*)ws;
  // Region B (32 MiB): XThi -> attnT
  u16*   XThi   = (u16*)(ws + 33554432);
  u16*   attnTb = (u16*)(ws + 33554432);
  // Region C (32 MiB): XTlo -> {Ghi, Glo, Tph, Tpl}
  u16*   XTlo  = (u16*)(ws + 67108864);
  u16*   Ghi   = (u16*)(ws + 67108864);
  u16*   Glo   = (u16*)(ws + 75497472);
  u16*   Tph   = (u16*)(ws + 83886080);
  u16*   Tpl   = (u16*)(ws + 92274688);
  u16*   Wqh   = (u16*)(ws + 100663296);
  u16*   Wql   = (u16*)(ws + 106954752);
  u16*   Vb    = (u16*)(ws + 113246208);
  u16*   Wpb   = (u16*)(ws + 146800640);

  // 1. x -> Xb + XThi/XTlo
  transpose_split_kernel<<<dim3(64, 16, 4), 256, 0, stream>>>(x, Xb, XThi, XTlo);
  // 2. weight converts
  convert_split_kernel<<<256, 256, 0, stream>>>(Wqkv, Wqh, Wql, 3145728 / 4);
  convert_kernel<<<128, 256, 0, stream>>>(Wproj, Wpb, 1048576 / 4);
  // 3. V = X @ Wv^T  (deep-pipelined 256x256; 256 blocks = 1/CU)
  gemm_pipe<true, false><<<dim3(64, 4, 1), 512, 0, stream>>>(
      Xb, Wqh + (size_t)2048 * 1024, Vb, nullptr, 16384, 1024, 1024,
      (size_t)0, (size_t)0, (size_t)0);
  // 3b. zero single-slice Gpart (aliases Xb; stream-ordered after step 3)
  hipMemsetAsync(Gpart, 0, (size_t)16777216, stream);
  // 4. pipelined symmetric Gram (256 uniform 72u ribbon jobs, atomic flush)
  gram_pipe<<<dim3(256), 512, 0, stream>>>(XThi, XTlo, Gpart);
  // 5. transpose-add reduce + hi/lo split (single slice; overwrites XTlo region)
  gram_reduce_split<<<dim3(16, 16, 4), 256, 0, stream>>>(Gpart, Ghi, Glo);
  // 6. T' = Wq G  (pipe4_core, 256 uniform blocks = 1/CU, 1 round)
  tprime_pipe<<<dim3(256), 512, 0, stream>>>(Wqh, Wql, Ghi, Glo, Tph, Tpl);
  // 7. fused S + softmax -> attn^T (512 thr, K-parity; overwrites XThi region)
  s_softmax_kernel<<<dim3(16, 4), 512, 0, stream>>>(Wqh, Wql, Tph, Tpl, alpha, attnTb);
  // 8. M_b = blockdiag(Wproj_h @ attn_bh) (overwrites Gpart region)
  m_build_kernel<<<dim3(8, 16, 4), 256, 0, stream>>>(Wpb, attnTb, Mb);
  // 9. Y_b = V_b @ M_b^T + bproj (fp32 out; deep-pipelined, 256 blocks)
  gemm_pipe<false, true><<<dim3(16, 4, 4), 512, 0, stream>>>(
      Vb, Mb, (float*)d_out, bproj, 4096, 1024, 1024,
      (size_t)1 << 22, (size_t)1 << 20, (size_t)1 << 22);
}

// Round 8
// 368.795 us; speedup vs baseline: 1.0350x; 1.0350x over previous
//
#include <hip/hip_runtime.h>
#include <hip/hip_bf16.h>
#include <cstdint>
#include <cstddef>

typedef unsigned short u16;
typedef __bf16 bf16x8 __attribute__((ext_vector_type(8)));
typedef float f32x4 __attribute__((ext_vector_type(4)));
typedef unsigned short u16x4 __attribute__((ext_vector_type(4)));
typedef unsigned short u16x8 __attribute__((ext_vector_type(8)));

#define AS1(p) ((__attribute__((address_space(1))) void*)(p))
#define AS3(p) ((__attribute__((address_space(3))) void*)(p))

__device__ __forceinline__ float bf2f(u16 u) {
  unsigned v = ((unsigned)u) << 16; float f; __builtin_memcpy(&f, &v, 4); return f;
}
__device__ __forceinline__ u16 f2bf(float f) {
  unsigned u; __builtin_memcpy(&u, &f, 4);
  u += 0x7FFFu + ((u >> 16) & 1u);   // RNE
  return (u16)(u >> 16);
}

// ---------------- fp32 -> bf16 convert (plain) ----------------
__global__ __launch_bounds__(256) void convert_kernel(const float* __restrict__ src,
                                                      u16* __restrict__ dst, int n4) {
  int i = blockIdx.x * blockDim.x + threadIdx.x;
  int stride = gridDim.x * blockDim.x;
  for (; i < n4; i += stride) {
    float4 v = ((const float4*)src)[i];
    u16x4 o;
    o.x = f2bf(v.x); o.y = f2bf(v.y); o.z = f2bf(v.z); o.w = f2bf(v.w);
    ((u16x4*)dst)[i] = o;
  }
}

// ---------------- fp32 -> bf16 hi + lo split ----------------
__global__ __launch_bounds__(256) void convert_split_kernel(const float* __restrict__ src,
                                                            u16* __restrict__ hi,
                                                            u16* __restrict__ lo, int n4) {
  int i = blockIdx.x * blockDim.x + threadIdx.x;
  int stride = gridDim.x * blockDim.x;
  for (; i < n4; i += stride) {
    float4 v = ((const float4*)src)[i];
    u16x4 oh, ol;
    oh.x = f2bf(v.x); ol.x = f2bf(v.x - bf2f(oh.x));
    oh.y = f2bf(v.y); ol.y = f2bf(v.y - bf2f(oh.y));
    oh.z = f2bf(v.z); ol.z = f2bf(v.z - bf2f(oh.z));
    oh.w = f2bf(v.w); ol.w = f2bf(v.w - bf2f(oh.w));
    ((u16x4*)hi)[i] = oh;
    ((u16x4*)lo)[i] = ol;
  }
}

// ---------------- transpose + split: x[b,n,c] fp32 -> Xb[b,n,c] bf16, XT{hi,lo}[b,c,n] ----------------
// Each thread owns a 4x4 block (rows r0..r0+3, cols c4..c4+3): registers transpose, then
// 4 u16x4 LDS stores per tensor (vs 16 scalar stores before — 4x fewer instrs, lower conflicts).
// Rotated layout rs = r0 ^ ((col>>2)&3)<<4 — rot in bits 4-5 commutes with +jj (bits 0-1),
// so the element (r,col) lands at col*72 + (r ^ rot) exactly as before; reader unchanged.
__global__ __launch_bounds__(256) void transpose_split_kernel(const float* __restrict__ x,
                                                              u16* __restrict__ Xb,
                                                              u16* __restrict__ XThi,
                                                              u16* __restrict__ XTlo) {
  __shared__ u16 lhi[64 * 72];
  __shared__ u16 llo[64 * 72];
  const int t  = threadIdx.x;
  const int nT = blockIdx.x, cT = blockIdx.y, b = blockIdx.z;
  const size_t xbase = ((size_t)b * 4096 + nT * 64) * 1024 + cT * 64;
  const int c4 = (t & 15) * 4;
  const int r0 = (t >> 4) * 4;
  const int rot = (t & 3) << 4;            // ((col>>2)&3)<<4 for all 4 cols of this block
  const int rs  = r0 ^ rot;
  u16 th[4][4], tl[4][4];                  // [i = col][jj = row]
#pragma unroll
  for (int jj = 0; jj < 4; ++jj) {
    const int r = r0 + jj;
    float4 v = *(const float4*)(x + xbase + (size_t)r * 1024 + c4);
    u16x4 hi;
    hi.x = f2bf(v.x); hi.y = f2bf(v.y); hi.z = f2bf(v.z); hi.w = f2bf(v.w);
    *(u16x4*)(Xb + xbase + (size_t)r * 1024 + c4) = hi;
    th[0][jj] = hi.x; th[1][jj] = hi.y; th[2][jj] = hi.z; th[3][jj] = hi.w;
    tl[0][jj] = f2bf(v.x - bf2f(hi.x));
    tl[1][jj] = f2bf(v.y - bf2f(hi.y));
    tl[2][jj] = f2bf(v.z - bf2f(hi.z));
    tl[3][jj] = f2bf(v.w - bf2f(hi.w));
  }
#pragma unroll
  for (int i = 0; i < 4; ++i) {
    u16x4 vh = { th[i][0], th[i][1], th[i][2], th[i][3] };
    u16x4 vl = { tl[i][0], tl[i][1], tl[i][2], tl[i][3] };
    *(u16x4*)(lhi + (c4 + i) * 72 + rs) = vh;
    *(u16x4*)(llo + (c4 + i) * 72 + rs) = vl;
  }
  __syncthreads();
  const int c  = t >> 2;
  const int n0 = (t & 3) * 16;
  const int rot_r = ((t >> 4) & 3) << 4;   // ((c>>2)&3)<<4 with c = t>>2
  const int nA = n0 ^ rot_r;
  const size_t tbase = ((size_t)b * 1024 + cT * 64 + c) * 4096 + nT * 64 + n0;
  *(u16x8*)(XThi + tbase)     = *(const u16x8*)(lhi + c * 72 + nA);
  *(u16x8*)(XThi + tbase + 8) = *(const u16x8*)(lhi + c * 72 + nA + 8);
  *(u16x8*)(XTlo + tbase)     = *(const u16x8*)(llo + c * 72 + nA);
  *(u16x8*)(XTlo + tbase + 8) = *(const u16x8*)(llo + c * 72 + nA + 8);
}

// ---------------- deep-pipelined 256x256 GEMM: C[M,N] = A[M,K] * B[N,K]^T ----------------
template<bool OUT_BF16, bool HAS_BIAS>
__global__ __launch_bounds__(512, 2) void gemm_pipe(const u16* __restrict__ A,
                                                    const u16* __restrict__ B,
                                                    void* __restrict__ Cv,
                                                    const float* __restrict__ bias,
                                                    int M, int N, int K,
                                                    size_t sA, size_t sB, size_t sC) {
  __shared__ __align__(16) u16 lds[4][2][8192];   // [ring][A|B][256 rows x 32 k] = 128 KiB
  const int tid  = threadIdx.x;
  const int lane = tid & 63;
  const int wave = tid >> 6;
  const int wm = wave >> 2, wn = wave & 3;
  const int rowTile = blockIdx.x * 256;
  const int colTile = blockIdx.y * 256;
  A += (size_t)blockIdx.z * sA;
  B += (size_t)blockIdx.z * sB;

  size_t srcA[2], srcB[2];
  int ldsOff[2];
#pragma unroll
  for (int j = 0; j < 2; ++j) {
    const int L = j * 512 + tid;           // 16B slot index 0..1023
    const int sr = L >> 3;                 // 128B superrow (2 rows)
    const int slot = (L & 7) ^ (sr & 7);   // logical slot within superrow
    const int r  = (sr << 1) | (slot >> 2);
    const int kq = slot & 3;
    srcA[j] = (size_t)(rowTile + r) * K + kq * 8;
    srcB[j] = (size_t)(colTile + r) * K + kq * 8;
    ldsOff[j] = (j * 512 + (tid & 448)) * 16;
  }

  const int m15 = lane & 15, kq4 = lane >> 4;
  const int r0a = wm * 128 + m15, sa0 = r0a >> 1;
  const int idxA0 = sa0 * 64 + (((((r0a & 1) << 2) | kq4)) ^ (sa0 & 7)) * 8;
  const int r0b = wn * 64 + m15, sb0 = r0b >> 1;
  const int idxB0 = sb0 * 64 + (((((r0b & 1) << 2) | kq4)) ^ (sb0 & 7)) * 8;

  const int NT = K >> 5;

  auto stageA = [&](int tt) {
    char* d = (char*)&lds[tt & 3][0][0];
    const int kt = tt << 5;
#pragma unroll
    for (int j = 0; j < 2; ++j)
      __builtin_amdgcn_global_load_lds(AS1(A + srcA[j] + kt), AS3(d + ldsOff[j]), 16, 0, 0);
  };
  auto stageB = [&](int tt) {
    char* d = (char*)&lds[tt & 3][1][0];
    const int kt = tt << 5;
#pragma unroll
    for (int j = 0; j < 2; ++j)
      __builtin_amdgcn_global_load_lds(AS1(B + srcB[j] + kt), AS3(d + ldsOff[j]), 16, 0, 0);
  };

  stageA(0); stageB(0);
  if (NT > 1) { stageA(1); stageB(1); }
  if (NT > 2) { stageA(2); stageB(2); }
  if (NT > 2) asm volatile("s_waitcnt vmcnt(8)" ::: "memory");
  else        asm volatile("s_waitcnt vmcnt(0)" ::: "memory");
  __builtin_amdgcn_sched_barrier(0);
  __builtin_amdgcn_s_barrier();
  __builtin_amdgcn_sched_barrier(0);

  f32x4 acc[8][4] = {};
  for (int t = 0; t < NT; ++t) {
    const u16* bufA = &lds[t & 3][0][0];
    const u16* bufB = &lds[t & 3][1][0];
    bf16x8 a[8], bfr[4];
#pragma unroll
    for (int ni = 0; ni < 4; ++ni) bfr[ni] = *(const bf16x8*)(bufB + idxB0 + ni * 512);
#pragma unroll
    for (int mi = 0; mi < 4; ++mi) a[mi] = *(const bf16x8*)(bufA + idxA0 + mi * 512);
    if (t + 3 < NT) stageA(t + 3);
    __builtin_amdgcn_sched_barrier(0);
    __builtin_amdgcn_s_barrier();
    __builtin_amdgcn_sched_barrier(0);
    __builtin_amdgcn_s_setprio(1);
#pragma unroll
    for (int mi = 0; mi < 4; ++mi)
#pragma unroll
      for (int ni = 0; ni < 4; ++ni)
        acc[mi][ni] = __builtin_amdgcn_mfma_f32_16x16x32_bf16(a[mi], bfr[ni], acc[mi][ni], 0, 0, 0);
    __builtin_amdgcn_s_setprio(0);
    __builtin_amdgcn_sched_barrier(0);
    __builtin_amdgcn_s_barrier();
    __builtin_amdgcn_sched_barrier(0);
#pragma unroll
    for (int mi = 4; mi < 8; ++mi) a[mi] = *(const bf16x8*)(bufA + idxA0 + mi * 512);
    if (t + 3 < NT) stageB(t + 3);
    __builtin_amdgcn_sched_barrier(0);
    __builtin_amdgcn_s_barrier();
    __builtin_amdgcn_sched_barrier(0);
    __builtin_amdgcn_s_setprio(1);
#pragma unroll
    for (int mi = 4; mi < 8; ++mi)
#pragma unroll
      for (int ni = 0; ni < 4; ++ni)
        acc[mi][ni] = __builtin_amdgcn_mfma_f32_16x16x32_bf16(a[mi], bfr[ni], acc[mi][ni], 0, 0, 0);
    __builtin_amdgcn_s_setprio(0);
    if (t < NT - 1) {
      if (t + 3 < NT)      asm volatile("s_waitcnt vmcnt(8)" ::: "memory");
      else if (t + 2 < NT) asm volatile("s_waitcnt vmcnt(4)" ::: "memory");
      else                 asm volatile("s_waitcnt vmcnt(0)" ::: "memory");
    }
    __builtin_amdgcn_sched_barrier(0);
    __builtin_amdgcn_s_barrier();
    __builtin_amdgcn_sched_barrier(0);
  }

  const int crow0 = rowTile + wm * 128 + (lane >> 4) * 4;
  const int ccol0 = colTile + wn * 64 + m15;
  if constexpr (OUT_BF16) {
    u16* C = (u16*)Cv + (size_t)blockIdx.z * sC;
#pragma unroll
    for (int mi = 0; mi < 8; ++mi)
#pragma unroll
      for (int ni = 0; ni < 4; ++ni) {
        const int col = ccol0 + ni * 16;
        const float bv = HAS_BIAS ? bias[col] : 0.f;
#pragma unroll
        for (int r = 0; r < 4; ++r)
          C[(size_t)(crow0 + mi * 16 + r) * N + col] = f2bf(acc[mi][ni][r] + bv);
      }
  } else {
    float* C = (float*)Cv + (size_t)blockIdx.z * sC;
#pragma unroll
    for (int mi = 0; mi < 8; ++mi)
#pragma unroll
      for (int ni = 0; ni < 4; ++ni) {
        const int col = ccol0 + ni * 16;
        const float bv = HAS_BIAS ? bias[col] : 0.f;
#pragma unroll
        for (int r = 0; r < 4; ++r)
          C[(size_t)(crow0 + mi * 16 + r) * N + col] = acc[mi][ni][r] + bv;
      }
  }
}

// ---------------- 4-tensor (hi/lo x A/B) pipelined 128x128 K-loop core (wave tile 64x32) ----------------
template<int L>
__device__ __forceinline__ void pipe4_core(const u16* __restrict__ pAh,
                                           const u16* __restrict__ pAl,
                                           const u16* __restrict__ pBh,
                                           const u16* __restrict__ pBl,
                                           u16* lds, int ldsByteOff,
                                           int idxA0, int idxB0, int bOff, int NT,
                                           f32x4 acc[4][2]) {
  auto stage2A = [&](int tt) {
    u16* d = lds + (tt & 3) * 16384;
    const int kt = tt << 5;
    __builtin_amdgcn_global_load_lds(AS1(pAh + kt), AS3((char*)d + ldsByteOff), 16, 0, 0);
    __builtin_amdgcn_global_load_lds(AS1(pAl + kt), AS3((char*)(d + 4096) + ldsByteOff), 16, 0, 0);
  };
  auto stage2B = [&](int tt) {
    if constexpr (L == 4) {
      u16* d = lds + (tt & 3) * 16384 + 8192;
      const int kt = tt << 5;
      __builtin_amdgcn_global_load_lds(AS1(pBh + kt), AS3((char*)d + ldsByteOff), 16, 0, 0);
      __builtin_amdgcn_global_load_lds(AS1(pBl + kt), AS3((char*)(d + 4096) + ldsByteOff), 16, 0, 0);
    }
  };

  stage2A(0); stage2B(0);
  stage2A(1); stage2B(1);
  stage2A(2); stage2B(2);
  if constexpr (L == 4) asm volatile("s_waitcnt vmcnt(8)" ::: "memory");
  else                  asm volatile("s_waitcnt vmcnt(4)" ::: "memory");
  __builtin_amdgcn_sched_barrier(0);
  __builtin_amdgcn_s_barrier();
  __builtin_amdgcn_sched_barrier(0);

  for (int t = 0; t < NT; ++t) {
    const u16* base = lds + (t & 3) * 16384;
    bf16x8 ah[4], al[4], bh[2], bl[2];
    bh[0] = *(const bf16x8*)(base + bOff + idxB0);
    bh[1] = *(const bf16x8*)(base + bOff + idxB0 + 512);
    bl[0] = *(const bf16x8*)(base + bOff + 4096 + idxB0);
    bl[1] = *(const bf16x8*)(base + bOff + 4096 + idxB0 + 512);
    ah[0] = *(const bf16x8*)(base + idxA0);
    ah[1] = *(const bf16x8*)(base + idxA0 + 512);
    al[0] = *(const bf16x8*)(base + 4096 + idxA0);
    al[1] = *(const bf16x8*)(base + 4096 + idxA0 + 512);
    if (t + 3 < NT) stage2A(t + 3);
    __builtin_amdgcn_sched_barrier(0);
    __builtin_amdgcn_s_barrier();
    __builtin_amdgcn_sched_barrier(0);
    __builtin_amdgcn_s_setprio(1);
#pragma unroll
    for (int mi = 0; mi < 2; ++mi)
#pragma unroll
      for (int ni = 0; ni < 2; ++ni) {
        acc[mi][ni] = __builtin_amdgcn_mfma_f32_16x16x32_bf16(ah[mi], bh[ni], acc[mi][ni], 0, 0, 0);
        acc[mi][ni] = __builtin_amdgcn_mfma_f32_16x16x32_bf16(ah[mi], bl[ni], acc[mi][ni], 0, 0, 0);
        acc[mi][ni] = __builtin_amdgcn_mfma_f32_16x16x32_bf16(al[mi], bh[ni], acc[mi][ni], 0, 0, 0);
      }
    __builtin_amdgcn_s_setprio(0);
    __builtin_amdgcn_sched_barrier(0);
    __builtin_amdgcn_s_barrier();
    __builtin_amdgcn_sched_barrier(0);
    ah[2] = *(const bf16x8*)(base + idxA0 + 1024);
    ah[3] = *(const bf16x8*)(base + idxA0 + 1536);
    al[2] = *(const bf16x8*)(base + 4096 + idxA0 + 1024);
    al[3] = *(const bf16x8*)(base + 4096 + idxA0 + 1536);
    if (t + 3 < NT) stage2B(t + 3);
    __builtin_amdgcn_sched_barrier(0);
    __builtin_amdgcn_s_barrier();
    __builtin_amdgcn_sched_barrier(0);
    __builtin_amdgcn_s_setprio(1);
#pragma unroll
    for (int mi = 2; mi < 4; ++mi)
#pragma unroll
      for (int ni = 0; ni < 2; ++ni) {
        acc[mi][ni] = __builtin_amdgcn_mfma_f32_16x16x32_bf16(ah[mi], bh[ni], acc[mi][ni], 0, 0, 0);
        acc[mi][ni] = __builtin_amdgcn_mfma_f32_16x16x32_bf16(ah[mi], bl[ni], acc[mi][ni], 0, 0, 0);
        acc[mi][ni] = __builtin_amdgcn_mfma_f32_16x16x32_bf16(al[mi], bh[ni], acc[mi][ni], 0, 0, 0);
      }
    __builtin_amdgcn_s_setprio(0);
    if (t < NT - 1) {
      if constexpr (L == 4) {
        if (t + 3 < NT)      asm volatile("s_waitcnt vmcnt(8)" ::: "memory");
        else if (t + 2 < NT) asm volatile("s_waitcnt vmcnt(4)" ::: "memory");
        else                 asm volatile("s_waitcnt vmcnt(0)" ::: "memory");
      } else {
        if (t + 3 < NT)      asm volatile("s_waitcnt vmcnt(4)" ::: "memory");
        else if (t + 2 < NT) asm volatile("s_waitcnt vmcnt(2)" ::: "memory");
        else                 asm volatile("s_waitcnt vmcnt(0)" ::: "memory");
      }
    }
    __builtin_amdgcn_sched_barrier(0);
    __builtin_amdgcn_s_barrier();
    __builtin_amdgcn_sched_barrier(0);
  }
}

// ---------------- 4-tensor K-pair pipelined 128x128 core, wave tile 64x64 (K-parity halves) ----------------
template<int L>
__device__ __forceinline__ void pipe4k_core(const u16* __restrict__ pAh,
                                            const u16* __restrict__ pAl,
                                            const u16* __restrict__ pBh,
                                            const u16* __restrict__ pBl,
                                            u16* lds, int ldsByteOff,
                                            int idxA0, int idxB0, int bOff,
                                            int NT, int half,
                                            f32x4 acc[4][4]) {
  auto stage = [&](int tt) {
    u16* d = lds + (tt & 3) * 16384;
    const int kt = tt << 5;
    __builtin_amdgcn_global_load_lds(AS1(pAh + kt), AS3((char*)d + ldsByteOff), 16, 0, 0);
    __builtin_amdgcn_global_load_lds(AS1(pAl + kt), AS3((char*)(d + 4096) + ldsByteOff), 16, 0, 0);
    if constexpr (L == 4) {
      __builtin_amdgcn_global_load_lds(AS1(pBh + kt), AS3((char*)(d + 8192) + ldsByteOff), 16, 0, 0);
      __builtin_amdgcn_global_load_lds(AS1(pBl + kt), AS3((char*)(d + 12288) + ldsByteOff), 16, 0, 0);
    }
  };

  stage(0); stage(1); stage(2); stage(3);
  if constexpr (L == 4) asm volatile("s_waitcnt vmcnt(8)" ::: "memory");
  else                  asm volatile("s_waitcnt vmcnt(4)" ::: "memory");
  __builtin_amdgcn_sched_barrier(0);
  __builtin_amdgcn_s_barrier();
  __builtin_amdgcn_sched_barrier(0);

  const int npairs = NT >> 1;
  for (int i = 0; i < npairs; ++i) {
    const u16* base = lds + ((2 * i + half) & 3) * 16384;
    bf16x8 ah[4], al[4], bh[4], bl[4];
#pragma unroll
    for (int ni = 0; ni < 4; ++ni) {
      bh[ni] = *(const bf16x8*)(base + bOff + idxB0 + ni * 512);
      bl[ni] = *(const bf16x8*)(base + bOff + 4096 + idxB0 + ni * 512);
    }
    ah[0] = *(const bf16x8*)(base + idxA0);
    ah[1] = *(const bf16x8*)(base + idxA0 + 512);
    al[0] = *(const bf16x8*)(base + 4096 + idxA0);
    al[1] = *(const bf16x8*)(base + 4096 + idxA0 + 512);
    __builtin_amdgcn_sched_barrier(0);
    __builtin_amdgcn_s_barrier();
    __builtin_amdgcn_sched_barrier(0);
    __builtin_amdgcn_s_setprio(1);
#pragma unroll
    for (int mi = 0; mi < 2; ++mi)
#pragma unroll
      for (int ni = 0; ni < 4; ++ni) {
        acc[mi][ni] = __builtin_amdgcn_mfma_f32_16x16x32_bf16(ah[mi], bh[ni], acc[mi][ni], 0, 0, 0);
        acc[mi][ni] = __builtin_amdgcn_mfma_f32_16x16x32_bf16(ah[mi], bl[ni], acc[mi][ni], 0, 0, 0);
        acc[mi][ni] = __builtin_amdgcn_mfma_f32_16x16x32_bf16(al[mi], bh[ni], acc[mi][ni], 0, 0, 0);
      }
    __builtin_amdgcn_s_setprio(0);
    __builtin_amdgcn_sched_barrier(0);
    __builtin_amdgcn_s_barrier();
    __builtin_amdgcn_sched_barrier(0);
    ah[2] = *(const bf16x8*)(base + idxA0 + 1024);
    ah[3] = *(const bf16x8*)(base + idxA0 + 1536);
    al[2] = *(const bf16x8*)(base + 4096 + idxA0 + 1024);
    al[3] = *(const bf16x8*)(base + 4096 + idxA0 + 1536);
    __builtin_amdgcn_sched_barrier(0);
    __builtin_amdgcn_s_barrier();
    __builtin_amdgcn_sched_barrier(0);
    if (i + 2 < npairs) { stage(2 * i + 4); stage(2 * i + 5); }
    __builtin_amdgcn_sched_barrier(0);
    __builtin_amdgcn_s_setprio(1);
#pragma unroll
    for (int mi = 2; mi < 4; ++mi)
#pragma unroll
      for (int ni = 0; ni < 4; ++ni) {
        acc[mi][ni] = __builtin_amdgcn_mfma_f32_16x16x32_bf16(ah[mi], bh[ni], acc[mi][ni], 0, 0, 0);
        acc[mi][ni] = __builtin_amdgcn_mfma_f32_16x16x32_bf16(ah[mi], bl[ni], acc[mi][ni], 0, 0, 0);
        acc[mi][ni] = __builtin_amdgcn_mfma_f32_16x16x32_bf16(al[mi], bh[ni], acc[mi][ni], 0, 0, 0);
      }
    __builtin_amdgcn_s_setprio(0);
    if (i < npairs - 1) {
      if (i + 2 < npairs) {
        if constexpr (L == 4) asm volatile("s_waitcnt vmcnt(8)" ::: "memory");
        else                  asm volatile("s_waitcnt vmcnt(4)" ::: "memory");
      } else {
        asm volatile("s_waitcnt vmcnt(0)" ::: "memory");
      }
    }
    __builtin_amdgcn_sched_barrier(0);
    __builtin_amdgcn_s_barrier();
    __builtin_amdgcn_sched_barrier(0);
  }
}

// ---------------- pipelined symmetric Gram (round-6 job map, K-pair core; measured best) ----------------
__global__ __launch_bounds__(512, 2) void gram_pipe(const u16* __restrict__ XThi,
                                                    const u16* __restrict__ XTlo,
                                                    float* __restrict__ Gpart) {
  __shared__ __align__(16) u16 ldsmem[4 * 4 * 4096];   // 128 KiB ring; reused for epilogue reduce
  const int tid = threadIdx.x, lane = tid & 63, wave = tid >> 6;
  const int q = wave & 3, half = wave >> 2;
  const int qm = q >> 1, qn = q & 1;
  const int bid = blockIdx.x;
  int b, rT, cT, slice, k0, NT; bool same = false;
  if (bid < 64) {
    b = bid & 3; const int j2 = bid >> 2;
    rT = cT = j2 >> 1; slice = j2 & 1; k0 = slice * 2048; NT = 64; same = true;
  } else {
    const int e = bid - 64; b = e & 3;
    const int idx = e >> 2; const int tile = idx >> 2, kq = idx & 3;
    int t = tile, rt = 0;
    while (t >= 7 - rt) { t -= 7 - rt; ++rt; }
    const int ct = rt + 1 + t;
    rT = rt; cT = ct;
    if (kq >= 2) { rT = ct; cT = rt; }
    slice = kq & 1; k0 = kq * 1024; NT = 32;
  }
  const int rowTile = rT * 128, colTile = cT * 128;
  const u16* Ah = XThi + ((size_t)b << 22);
  const u16* Al = XTlo + ((size_t)b << 22);

  const int sr = tid >> 3;
  const int slot = (tid & 7) ^ (sr & 7);
  const int r = (sr << 1) | (slot >> 2);
  const int kq8 = (slot & 3) * 8;
  const u16* pAh = Ah + (size_t)(rowTile + r) * 4096 + k0 + kq8;
  const u16* pAl = Al + (size_t)(rowTile + r) * 4096 + k0 + kq8;
  const u16* pBh = Ah + (size_t)(colTile + r) * 4096 + k0 + kq8;
  const u16* pBl = Al + (size_t)(colTile + r) * 4096 + k0 + kq8;
  const int ldsByteOff = (tid & 448) * 16;

  const int m15 = lane & 15, kq4 = lane >> 4;
  const int r0a = qm * 64 + m15, sa0 = r0a >> 1;
  const int idxA0 = sa0 * 64 + (((((r0a & 1) << 2) | kq4)) ^ (sa0 & 7)) * 8;
  const int r0b = qn * 64 + m15, sb0 = r0b >> 1;
  const int idxB0 = sb0 * 64 + (((((r0b & 1) << 2) | kq4)) ^ (sb0 & 7)) * 8;

  f32x4 acc[4][4] = {};
  if (same) pipe4k_core<2>(pAh, pAl, pAh, pAl, ldsmem, ldsByteOff, idxA0, idxB0, 0, NT, half, acc);
  else      pipe4k_core<4>(pAh, pAl, pBh, pBl, ldsmem, ldsByteOff, idxA0, idxB0, 8192, NT, half, acc);

  float* red = (float*)ldsmem;
  const int rr = (lane >> 4) * 4;
  if (half) {
#pragma unroll
    for (int mi = 0; mi < 4; ++mi)
#pragma unroll
      for (int ni = 0; ni < 4; ++ni)
        *(f32x4*)(red + q * 4352 + (ni * 16 + m15) * 68 + mi * 16 + rr) = acc[mi][ni];
  }
  __syncthreads();
  if (!half) {
    float* out = Gpart + ((size_t)(slice * 4 + b) << 20);
    const int crow0 = rowTile + qm * 64 + rr;
    const int ccol0 = colTile + qn * 64 + m15;
#pragma unroll
    for (int mi = 0; mi < 4; ++mi)
#pragma unroll
      for (int ni = 0; ni < 4; ++ni) {
        f32x4 v = *(const f32x4*)(red + q * 4352 + (ni * 16 + m15) * 68 + mi * 16 + rr);
        v += acc[mi][ni];
#pragma unroll
        for (int r4 = 0; r4 < 4; ++r4)
          out[(size_t)(crow0 + mi * 16 + r4) * 1024 + ccol0 + ni * 16] = v[r4];
      }
  }
}

// ---------------- tiled reduce: G = s0+s1 (r,c) [+ (s0+s1)(c,r)^T if off-diag-128] ----------------
__global__ __launch_bounds__(256) void gram_reduce_split(const float* __restrict__ Gp,
                                                         u16* __restrict__ Ghi,
                                                         u16* __restrict__ Glo) {
  const int rt = blockIdx.x, ct = blockIdx.y, b = blockIdx.z;  // 64x64 tiles
  const bool diag128 = (rt >> 1) == (ct >> 1);
  const float* s0 = Gp + ((size_t)b << 20);
  const float* s1 = Gp + ((size_t)(4 + b) << 20);
  __shared__ float lT[64 * 68];
  const int t = threadIdx.x;
  const int r = t >> 2;
  const int c16 = (t & 3) * 16;

  if (!diag128) {
    const size_t bb = (size_t)(ct * 64 + r) * 1024 + rt * 64 + c16;
#pragma unroll
    for (int q = 0; q < 4; ++q) {
      float4 v0 = *(const float4*)(s0 + bb + q * 4);
      float4 v1 = *(const float4*)(s1 + bb + q * 4);
      float4 s = { v0.x + v1.x, v0.y + v1.y, v0.z + v1.z, v0.w + v1.w };
      *(float4*)(lT + r * 68 + c16 + q * 4) = s;
    }
    __syncthreads();
  }

  const size_t ab = (size_t)(rt * 64 + r) * 1024 + ct * 64 + c16;
  const size_t ob = ((size_t)b << 20) + ab;
#pragma unroll
  for (int q = 0; q < 4; ++q) {
    float4 v0 = *(const float4*)(s0 + ab + q * 4);
    float4 v1 = *(const float4*)(s1 + ab + q * 4);
    float g[4] = { v0.x + v1.x, v0.y + v1.y, v0.z + v1.z, v0.w + v1.w };
    if (!diag128) {
#pragma unroll
      for (int i = 0; i < 4; ++i) g[i] += lT[(c16 + q * 4 + i) * 68 + r];
    }
    u16x4 oh, ol;
    oh.x = f2bf(g[0]); ol.x = f2bf(g[0] - bf2f(oh.x));
    oh.y = f2bf(g[1]); ol.y = f2bf(g[1] - bf2f(oh.y));
    oh.z = f2bf(g[2]); ol.z = f2bf(g[2] - bf2f(oh.z));
    oh.w = f2bf(g[3]); ol.w = f2bf(g[3] - bf2f(oh.w));
    *(u16x4*)(Ghi + ob + q * 4) = oh;
    *(u16x4*)(Glo + ob + q * 4) = ol;
  }
}

// ---------------- pipelined T' = Wq * G (G symmetric), pipe4_core, split-bf16 out ----------------
// 256 uniform blocks (64 tiles x 4 batches), K=1024: one block per CU, one round.
__global__ __launch_bounds__(512, 2) void tprime_pipe(const u16* __restrict__ Wqh,
                                                      const u16* __restrict__ Wql,
                                                      const u16* __restrict__ Ghi,
                                                      const u16* __restrict__ Glo,
                                                      u16* __restrict__ Tph,
                                                      u16* __restrict__ Tpl) {
  __shared__ __align__(16) u16 lds[4 * 4 * 4096];   // 128 KiB
  const int tid = threadIdx.x, lane = tid & 63, wave = tid >> 6;
  const int wm = wave >> 2, wn = wave & 3;
  const int bid = blockIdx.x;
  const int b = bid & 3, tile = bid >> 2;
  const int rowTile = (tile >> 3) * 128, colTile = (tile & 7) * 128;
  const size_t zoff = (size_t)b << 20;

  const int sr = tid >> 3;
  const int slot = (tid & 7) ^ (sr & 7);
  const int r = (sr << 1) | (slot >> 2);
  const int kq8 = (slot & 3) * 8;
  const u16* pAh = Wqh + (size_t)(rowTile + r) * 1024 + kq8;
  const u16* pAl = Wql + (size_t)(rowTile + r) * 1024 + kq8;
  const u16* pBh = Ghi + zoff + (size_t)(colTile + r) * 1024 + kq8;
  const u16* pBl = Glo + zoff + (size_t)(colTile + r) * 1024 + kq8;
  const int ldsByteOff = (tid & 448) * 16;

  const int m15 = lane & 15, kq4 = lane >> 4;
  const int r0a = wm * 64 + m15, sa0 = r0a >> 1;
  const int idxA0 = sa0 * 64 + (((((r0a & 1) << 2) | kq4)) ^ (sa0 & 7)) * 8;
  const int r0b = wn * 32 + m15, sb0 = r0b >> 1;
  const int idxB0 = sb0 * 64 + (((((r0b & 1) << 2) | kq4)) ^ (sb0 & 7)) * 8;

  f32x4 acc[4][2] = {};
  pipe4_core<4>(pAh, pAl, pBh, pBl, lds, ldsByteOff, idxA0, idxB0, 8192, 32, acc);

  const int crow0 = rowTile + wm * 64 + (lane >> 4) * 4;
  const int ccol0 = colTile + wn * 32 + m15;
#pragma unroll
  for (int mi = 0; mi < 4; ++mi)
#pragma unroll
    for (int ni = 0; ni < 2; ++ni)
#pragma unroll
      for (int r4 = 0; r4 < 4; ++r4) {
        float v = acc[mi][ni][r4];
        u16 hi = f2bf(v);
        u16 lo = f2bf(v - bf2f(hi));
        size_t off = zoff + (size_t)(crow0 + mi * 16 + r4) * 1024 + ccol0 + ni * 16;
        Tph[off] = hi;
        Tpl[off] = lo;
      }
}

// ---------------- fused S + softmax -> attn^T, 512 thr K-parity + swizzled LDS ----------------
__global__ __launch_bounds__(512) void s_softmax_kernel(const u16* __restrict__ Wqh,
                                                        const u16* __restrict__ Wql,
                                                        const u16* __restrict__ Tph,
                                                        const u16* __restrict__ Tpl,
                                                        const float* __restrict__ alpha,
                                                        u16* __restrict__ attnT) {
  const int h = blockIdx.x, b = blockIdx.y;
  const int tid = threadIdx.x, lane = tid & 63, wave = tid >> 6;
  const int half = wave >> 2, w4 = wave & 3;
  __shared__ __align__(16) u16 sm[2][4][64 * 32];   // [set][Ah,Al,Bh,Bl] = 32 KiB

  const size_t aBase = (size_t)(1024 + h * 64) * 1024;
  const size_t bBase = ((size_t)b << 20) + (size_t)(h * 64) * 1024;

  const int tid2 = tid & 255;
  const int sr = tid2 >> 3;
  const int slot = (tid2 & 7) ^ (sr & 7);
  const int r = (sr << 1) | (slot >> 2);
  const int kq8 = (slot & 3) * 8;
  const u16* pAh = Wqh + aBase + (size_t)r * 1024 + kq8;
  const u16* pAl = Wql + aBase + (size_t)r * 1024 + kq8;
  const u16* pBh = Tph + bBase + (size_t)r * 1024 + kq8;
  const u16* pBl = Tpl + bBase + (size_t)r * 1024 + kq8;
  const int off = (tid2 & 192) * 16;

  const int m = lane & 15, kq4 = lane >> 4;
  const int rA = w4 * 16 + m, sA0 = rA >> 1;
  const int idxA = sA0 * 64 + (((((rA & 1) << 2) | kq4)) ^ (sA0 & 7)) * 8;
  int idxB[4];
#pragma unroll
  for (int cb = 0; cb < 4; ++cb) {
    const int rB = cb * 16 + m, sB0 = rB >> 1;
    idxB[cb] = sB0 * 64 + (((((rB & 1) << 2) | kq4)) ^ (sB0 & 7)) * 8;
  }

  f32x4 acc[4] = {};
  for (int i = 0; i < 16; ++i) {
    const int kt = (2 * i + half) * 32;
    __builtin_amdgcn_global_load_lds(AS1(pAh + kt), AS3((char*)&sm[half][0][0] + off), 16, 0, 0);
    __builtin_amdgcn_global_load_lds(AS1(pAl + kt), AS3((char*)&sm[half][1][0] + off), 16, 0, 0);
    __builtin_amdgcn_global_load_lds(AS1(pBh + kt), AS3((char*)&sm[half][2][0] + off), 16, 0, 0);
    __builtin_amdgcn_global_load_lds(AS1(pBl + kt), AS3((char*)&sm[half][3][0] + off), 16, 0, 0);
    __syncthreads();
    bf16x8 ah = *(const bf16x8*)(&sm[half][0][0] + idxA);
    bf16x8 al = *(const bf16x8*)(&sm[half][1][0] + idxA);
#pragma unroll
    for (int cb = 0; cb < 4; ++cb) {
      bf16x8 bh = *(const bf16x8*)(&sm[half][2][0] + idxB[cb]);
      bf16x8 bl = *(const bf16x8*)(&sm[half][3][0] + idxB[cb]);
      acc[cb] = __builtin_amdgcn_mfma_f32_16x16x32_bf16(ah, bh, acc[cb], 0, 0, 0);
      acc[cb] = __builtin_amdgcn_mfma_f32_16x16x32_bf16(ah, bl, acc[cb], 0, 0, 0);
      acc[cb] = __builtin_amdgcn_mfma_f32_16x16x32_bf16(al, bh, acc[cb], 0, 0, 0);
    }
    __syncthreads();
  }

  float* red = (float*)&sm[0][0][0];
  const int rbase = (w4 * 64 + lane) * 20;
  if (half) {
#pragma unroll
    for (int cb = 0; cb < 4; ++cb)
      *(f32x4*)(red + rbase + cb * 4) = acc[cb];
  }
  __syncthreads();
  if (!half) {
#pragma unroll
    for (int cb = 0; cb < 4; ++cb)
      acc[cb] += *(const f32x4*)(red + rbase + cb * 4);

    const float invA = 1.f / alpha[h];
    const int g = lane >> 4;
    const size_t obase = (size_t)(b * 16 + h) * 4096;
#pragma unroll
    for (int rr = 0; rr < 4; ++rr) {
      int d = w4 * 16 + g * 4 + rr;
      float s[4];
#pragma unroll
      for (int cb = 0; cb < 4; ++cb) s[cb] = acc[cb][rr] * invA;
      float mx = fmaxf(fmaxf(s[0], s[1]), fmaxf(s[2], s[3]));
#pragma unroll
      for (int o = 1; o < 16; o <<= 1) mx = fmaxf(mx, __shfl_xor(mx, o, 64));
      float e[4]; float sum = 0.f;
#pragma unroll
      for (int cb = 0; cb < 4; ++cb) { e[cb] = __expf(s[cb] - mx); sum += e[cb]; }
#pragma unroll
      for (int o = 1; o < 16; o <<= 1) sum += __shfl_xor(sum, o, 64);
      float inv = 1.f / sum;
#pragma unroll
      for (int cb = 0; cb < 4; ++cb) {
        int e_idx = cb * 16 + (lane & 15);
        attnT[obase + (size_t)e_idx * 64 + d] = f2bf(e[cb] * inv);
      }
    }
  }
}

// ---------------- M_b[o, h*64+e] = sum_d Wproj[o, h*64+d] * attn_bh[d,e] ----------------
__global__ __launch_bounds__(256) void m_build_kernel(const u16* __restrict__ Wpb,
                                                      const u16* __restrict__ attnT,
                                                      u16* __restrict__ Mb) {
  const int oT = blockIdx.x, h = blockIdx.y, b = blockIdx.z;
  const int tid = threadIdx.x, lane = tid & 63, wave = tid >> 6;
  __shared__ __align__(16) u16 lA[128 * 64];   // Wproj tile [o 128][d 64]
  __shared__ __align__(16) u16 lB[64 * 64];    // attnT [e 64][d 64]
  const int bh = b * 16 + h;
#pragma unroll
  for (int i = 0; i < 4; ++i) {
    int idx = i * 256 + tid;
    int row = idx >> 3;
    int kc  = (idx & 7) * 8;
    int ldsOff = (i * 256 + (tid & 192)) * 16;
    __builtin_amdgcn_global_load_lds(AS1(Wpb + (size_t)(oT * 128 + row) * 1024 + h * 64 + kc),
                                     AS3((char*)lA + ldsOff), 16, 0, 0);
  }
#pragma unroll
  for (int i = 0; i < 2; ++i) {
    int idx = i * 256 + tid;
    int ldsOff = (i * 256 + (tid & 192)) * 16;
    __builtin_amdgcn_global_load_lds(AS1(attnT + (size_t)bh * 4096 + idx * 8),
                                     AS3((char*)lB + ldsOff), 16, 0, 0);
  }
  __syncthreads();
  const int m  = lane & 15;
  const int ko = (lane >> 4) * 8;
  const int wr = wave * 32;
  f32x4 acc[2][4] = {};
#pragma unroll
  for (int ks = 0; ks < 2; ++ks) {
#pragma unroll
    for (int rb = 0; rb < 2; ++rb) {
      bf16x8 a = *(const bf16x8*)(lA + (wr + rb * 16 + m) * 64 + ks * 32 + ko);
#pragma unroll
      for (int cb = 0; cb < 4; ++cb) {
        bf16x8 bb = *(const bf16x8*)(lB + (cb * 16 + m) * 64 + ks * 32 + ko);
        acc[rb][cb] = __builtin_amdgcn_mfma_f32_16x16x32_bf16(a, bb, acc[rb][cb], 0, 0, 0);
      }
    }
  }
  u16* out = Mb + ((size_t)b << 20);
#pragma unroll
  for (int rb = 0; rb < 2; ++rb)
#pragma unroll
    for (int cb = 0; cb < 4; ++cb) {
      int col = h * 64 + cb * 16 + (lane & 15);
#pragma unroll
      for (int r = 0; r < 4; ++r) {
        int row = oT * 128 + wr + rb * 16 + (lane >> 4) * 4 + r;
        out[(size_t)row * 1024 + col] = f2bf(acc[rb][cb][r]);
      }
    }
}

extern "C" void kernel_launch(void* const* d_in, const int* in_sizes, int n_in,
                              void* d_out, int out_size, void* d_ws, size_t ws_size,
                              hipStream_t stream) {
  const float* x     = (const float*)d_in[0];
  const float* Wqkv  = (const float*)d_in[3];
  const float* Wproj = (const float*)d_in[4];
  const float* bproj = (const float*)d_in[5];
  const float* alpha = (const float*)d_in[6];

  char* ws = (char*)d_ws;
  // Region A (32 MiB): Xb -> Gpart -> Mb
  u16*   Xb     = (u16*)ws;
  float* Gpart  = (float*)ws;
  u16*   Mb     = (u16*)ws;
  // Region B (32 MiB): XThi -> attnT
  u16*   XThi   = (u16*)(ws + 33554432);
  u16*   attnTb = (u16*)(ws + 33554432);
  // Region C (32 MiB): XTlo -> {Ghi, Glo, Tph, Tpl}
  u16*   XTlo  = (u16*)(ws + 67108864);
  u16*   Ghi   = (u16*)(ws + 67108864);
  u16*   Glo   = (u16*)(ws + 75497472);
  u16*   Tph   = (u16*)(ws + 83886080);
  u16*   Tpl   = (u16*)(ws + 92274688);
  u16*   Wqh   = (u16*)(ws + 100663296);
  u16*   Wql   = (u16*)(ws + 106954752);
  u16*   Vb    = (u16*)(ws + 113246208);
  u16*   Wpb   = (u16*)(ws + 146800640);

  // 1. x -> Xb + XThi/XTlo (register-transpose + u16x4 LDS stores)
  transpose_split_kernel<<<dim3(64, 16, 4), 256, 0, stream>>>(x, Xb, XThi, XTlo);
  // 2. weight converts
  convert_split_kernel<<<256, 256, 0, stream>>>(Wqkv, Wqh, Wql, 3145728 / 4);
  convert_kernel<<<128, 256, 0, stream>>>(Wproj, Wpb, 1048576 / 4);
  // 3. V = X @ Wv^T  (deep-pipelined 256x256; 256 blocks = 1/CU)
  gemm_pipe<true, false><<<dim3(64, 4, 1), 512, 0, stream>>>(
      Xb, Wqh + (size_t)2048 * 1024, Vb, nullptr, 16384, 1024, 1024,
      (size_t)0, (size_t)0, (size_t)0);
  // 4. pipelined symmetric Gram partials (512 jobs, diag-first, K-pair core)
  gram_pipe<<<dim3(512), 512, 0, stream>>>(XThi, XTlo, Gpart);
  // 5. transpose-add reduce + hi/lo split (overwrites XTlo region)
  gram_reduce_split<<<dim3(16, 16, 4), 256, 0, stream>>>(Gpart, Ghi, Glo);
  // 6. T' = Wq G  (pipe4_core, 256 uniform blocks = 1/CU, 1 round)
  tprime_pipe<<<dim3(256), 512, 0, stream>>>(Wqh, Wql, Ghi, Glo, Tph, Tpl);
  // 7. fused S + softmax -> attn^T (512 thr, K-parity; overwrites XThi region)
  s_softmax_kernel<<<dim3(16, 4), 512, 0, stream>>>(Wqh, Wql, Tph, Tpl, alpha, attnTb);
  // 8. M_b = blockdiag(Wproj_h @ attn_bh) (overwrites Gpart region)
  m_build_kernel<<<dim3(8, 16, 4), 256, 0, stream>>>(Wpb, attnTb, Mb);
  // 9. Y_b = V_b @ M_b^T + bproj (fp32 out; deep-pipelined, 256 blocks)
  gemm_pipe<false, true><<<dim3(16, 4, 4), 512, 0, stream>>>(
      Vb, Mb, (float*)d_out, bproj, 4096, 1024, 1024,
      (size_t)1 << 22, (size_t)1 << 20, (size_t)1 << 22);
}